// Round 9
// baseline (328.147 us; speedup 1.0000x reference)
//
#include <hip/hip_runtime.h>

#define N_NODES 100000
#define N_EDGES 1600000
#define NBUCK 196      // ceil(100000/512) coarse buckets
#define BSH 9          // 512 nodes per bucket

typedef __attribute__((ext_vector_type(8))) short short8;
typedef __attribute__((ext_vector_type(4))) float f32x4;

__device__ __forceinline__ float bflo(unsigned int u) { return __uint_as_float(u << 16); }
__device__ __forceinline__ float bfhi(unsigned int u) { return __uint_as_float(u & 0xffff0000u); }
__device__ __forceinline__ unsigned short f2bf(float f) {
    unsigned int u = __float_as_uint(f);
    return (unsigned short)((u + 0x7fffu + ((u >> 16) & 1u)) >> 16);   // RNE
}
__device__ __forceinline__ unsigned int pk2(float a, float b) {
    return (unsigned int)f2bf(a) | ((unsigned int)f2bf(b) << 16);
}

// ================= fused cast x->bf16 + degree histogram =================
__global__ __launch_bounds__(256) void k_cast_hist(const float* __restrict__ x, unsigned short* __restrict__ xh,
                                                   const int* __restrict__ dst, int* __restrict__ deg) {
    int i = blockIdx.x * 256 + threadIdx.x;     // 1.6M threads: 4 x-elems + 1 edge each
    float4 v = *reinterpret_cast<const float4*>(x + (size_t)i * 4);
    ushort4 o;
    o.x = f2bf(v.x); o.y = f2bf(v.y); o.z = f2bf(v.z); o.w = f2bf(v.w);
    *reinterpret_cast<ushort4*>(xh + (size_t)i * 4) = o;
    atomicAdd(&deg[dst[i]], 1);
}

// ================= CSR scan chain =================
__global__ __launch_bounds__(1024) void k_part_scan(const int* __restrict__ deg,
                                                    int* __restrict__ rowstart, int* __restrict__ bsum) {
    __shared__ int wsum[16];
    const int tid = threadIdx.x, lane = tid & 63, wid = tid >> 6;
    int i = blockIdx.x * 1024 + tid;
    int v = (i < N_NODES) ? deg[i] : 0;
    int s = v;
    #pragma unroll
    for (int off = 1; off < 64; off <<= 1) {
        int t = __shfl_up(s, off);
        if (lane >= off) s += t;
    }
    if (lane == 63) wsum[wid] = s;
    __syncthreads();
    if (tid < 16) {
        int w = wsum[tid];
        #pragma unroll
        for (int off = 1; off < 16; off <<= 1) {
            int t = __shfl_up(w, off);
            if (tid >= off) w += t;
        }
        wsum[tid] = w;
    }
    __syncthreads();
    int wexcl = (wid == 0) ? 0 : wsum[wid - 1];
    if (i < N_NODES) rowstart[i] = wexcl + s - v;
    if (tid == 1023) bsum[blockIdx.x] = wexcl + s;
}

// scan of 98 block sums; also writes rowstart[N] and initializes bucket cursors
__global__ __launch_bounds__(128) void k_scan_bsum(const int* __restrict__ bsum, int* __restrict__ boff,
                                                   int* __restrict__ rowstart, int* __restrict__ ccur, int nblk) {
    __shared__ int sh[128];
    __shared__ int excl[128];
    int t = threadIdx.x;
    int v = (t < nblk) ? bsum[t] : 0;
    int acc = v;
    sh[t] = acc;
    __syncthreads();
    #pragma unroll
    for (int off = 1; off < 128; off <<= 1) {
        int add = (t >= off) ? sh[t - off] : 0;
        __syncthreads();
        acc += add;
        sh[t] = acc;
        __syncthreads();
    }
    if (t < nblk) boff[t] = acc - v;
    excl[t] = acc - v;
    if (t == nblk - 1) rowstart[N_NODES] = acc;
    __syncthreads();
    for (int c = t; c < NBUCK; c += 128)   // ccur[c] = final rowstart at bucket start
        ccur[c] = rowstart[c << BSH] + excl[c >> 1];   // (c<<9)>>10 == c>>1
}

__global__ __launch_bounds__(1024) void k_add_off(const int* __restrict__ boff, int* __restrict__ rowstart) {
    int i = blockIdx.x * 1024 + threadIdx.x;
    if (i < N_NODES) rowstart[i] += boff[blockIdx.x];
}

// ================= CSR build pass 1: coarse bucket (counting sort, packed pairs) =================
#define EPT 16
__global__ __launch_bounds__(256) void k_bucket(const int* __restrict__ src, const int* __restrict__ dst,
                                                int* __restrict__ ccur, unsigned int* __restrict__ pairs) {
    __shared__ int cnt[NBUCK];
    __shared__ int base[NBUCK];
    const int tid = threadIdx.x;
    const int e_base = blockIdx.x * (256 * EPT);
    for (int i = tid; i < NBUCK; i += 256) cnt[i] = 0;
    __syncthreads();
    #pragma unroll
    for (int i = 0; i < EPT; ++i) {              // phase A: local histogram
        int e = e_base + i * 256 + tid;
        if (e < N_EDGES) atomicAdd(&cnt[dst[e] >> BSH], 1);
    }
    __syncthreads();
    for (int i = tid; i < NBUCK; i += 256) {     // phase B: reserve global ranges
        int c = cnt[i];
        base[i] = (c > 0) ? atomicAdd(&ccur[i], c) : 0;
        cnt[i] = 0;
    }
    __syncthreads();
    #pragma unroll
    for (int i = 0; i < EPT; ++i) {              // phase C: grouped scatter
        int e = e_base + i * 256 + tid;
        if (e < N_EDGES) {
            int d = dst[e];
            int bkt = d >> BSH;
            int off = atomicAdd(&cnt[bkt], 1);
            pairs[base[bkt] + off] = ((unsigned int)(d & 511) << 17) | (unsigned int)src[e];
        }
    }
}

// ================= CSR build pass 2: within-bucket exact scatter (LDS cursors) =================
__global__ __launch_bounds__(256) void k_scatter_csr(const int* __restrict__ rowstart,
                                                     const unsigned int* __restrict__ pairs,
                                                     int* __restrict__ srcs) {
    __shared__ int lcur[512];
    const int c = blockIdx.x, tid = threadIdx.x;
    const int nbase = c << BSH;
    for (int i = tid; i < 512; i += 256) {
        int n = nbase + i;
        lcur[i] = (n < N_NODES) ? rowstart[n] : 0;
    }
    __syncthreads();
    int e0 = rowstart[nbase];
    int nend = nbase + 512; if (nend > N_NODES) nend = N_NODES;
    int e1 = rowstart[nend];
    for (int e = e0 + tid; e < e1; e += 256) {
        unsigned int u = pairs[e];
        int dloc = (int)(u >> 17);
        int p = atomicAdd(&lcur[dloc], 1);
        srcs[p] = (int)(u & 0x1FFFFu);
    }
}

// ================= weight prepack into MFMA fragment order (bf16) =================
__global__ __launch_bounds__(256) void k_pack(const float* __restrict__ Wl1, const float* __restrict__ Wr1,
                                              const float* __restrict__ Wl2, const float* __restrict__ Wr2,
                                              unsigned short* __restrict__ Bp1, unsigned short* __restrict__ Bp2) {
    int idx = blockIdx.x * 256 + threadIdx.x;   // 49152 threads
    if (idx < 16384) {                          // layer1: K=128
        int j = idx & 7, g = (idx >> 3) & 3, col = (idx >> 5) & 127, kk = idx >> 12;
        int r = kk * 32 + g * 8 + j;
        float w = (r < 64) ? Wl1[r * 128 + col] : Wr1[(r - 64) * 128 + col];
        Bp1[idx] = f2bf(w);
    } else {                                    // layer2: K=256
        int q = idx - 16384;
        int j = q & 7, g = (q >> 3) & 3, col = (q >> 5) & 127, kk = q >> 12;
        int r = kk * 32 + g * 8 + j;
        float w = (r < 128) ? Wl2[r * 128 + col] : Wr2[(r - 128) * 128 + col];
        Bp2[q] = f2bf(w);
    }
}

// ================= layer 1: grouped-x4 gather + MFMA dense + relu -> bf16 h1h =================
// Gather: 8 lane-groups of 8; one dwordx4 wave-load covers 8 edges' 128B rows.
__global__ __launch_bounds__(256, 8) void k_layer1(
    const unsigned short* __restrict__ xh,
    const int* __restrict__ rowstart, const int* __restrict__ srcs,
    const unsigned short* __restrict__ Bp1, const float* __restrict__ b,
    unsigned short* __restrict__ h1h)
{
    __shared__ unsigned short A[32][136];
    __shared__ int rs[33];
    const int tile = blockIdx.x * 32;           // 100000 = 3125*32
    const int tid = threadIdx.x, lane = tid & 63, wid = tid >> 6;

    if (tid < 33) rs[tid] = rowstart[tile + tid];
    {   // root rows -> cols 64..127
        int node = tid >> 3, part = tid & 7;
        uint4 v = *reinterpret_cast<const uint4*>(xh + (((unsigned)(tile + node)) << 6) + part * 8);
        *reinterpret_cast<uint4*>(&A[node][64 + part * 8]) = v;
    }
    __syncthreads();

    const int g = lane >> 3;                    // edge group 0..7
    const int q = lane & 7;                     // 16B chunk -> features 8q..8q+7
    for (int it = 0; it < 8; ++it) {
        int nl = wid * 8 + it;
        int e0 = rs[nl], e1 = rs[nl + 1];
        float f0 = 0.f, f1 = 0.f, f2 = 0.f, f3 = 0.f, f4 = 0.f, f5 = 0.f, f6 = 0.f, f7 = 0.f;
        int e = e0;
        for (; e + 8 <= e1; e += 8) {
            int s = srcs[e + g];
            uint4 u = *reinterpret_cast<const uint4*>(xh + (((unsigned)s) << 6) + q * 8);
            f0 += bflo(u.x); f1 += bfhi(u.x);
            f2 += bflo(u.y); f3 += bfhi(u.y);
            f4 += bflo(u.z); f5 += bfhi(u.z);
            f6 += bflo(u.w); f7 += bfhi(u.w);
        }
        for (; e < e1; ++e) {
            if (g == 0) {
                uint4 u = *reinterpret_cast<const uint4*>(xh + (((unsigned)srcs[e]) << 6) + q * 8);
                f0 += bflo(u.x); f1 += bfhi(u.x);
                f2 += bflo(u.y); f3 += bfhi(u.y);
                f4 += bflo(u.z); f5 += bfhi(u.z);
                f6 += bflo(u.w); f7 += bfhi(u.w);
            }
        }
        // reduce across 8 edge-groups (lanes with same q)
        f0 += __shfl_xor(f0, 8); f0 += __shfl_xor(f0, 16); f0 += __shfl_xor(f0, 32);
        f1 += __shfl_xor(f1, 8); f1 += __shfl_xor(f1, 16); f1 += __shfl_xor(f1, 32);
        f2 += __shfl_xor(f2, 8); f2 += __shfl_xor(f2, 16); f2 += __shfl_xor(f2, 32);
        f3 += __shfl_xor(f3, 8); f3 += __shfl_xor(f3, 16); f3 += __shfl_xor(f3, 32);
        f4 += __shfl_xor(f4, 8); f4 += __shfl_xor(f4, 16); f4 += __shfl_xor(f4, 32);
        f5 += __shfl_xor(f5, 8); f5 += __shfl_xor(f5, 16); f5 += __shfl_xor(f5, 32);
        f6 += __shfl_xor(f6, 8); f6 += __shfl_xor(f6, 16); f6 += __shfl_xor(f6, 32);
        f7 += __shfl_xor(f7, 8); f7 += __shfl_xor(f7, 16); f7 += __shfl_xor(f7, 32);
        int d = e1 - e0;
        float rd = (d > 0) ? (1.0f / (float)d) : 1.0f;
        if (g == 0) {
            uint4 p;
            p.x = pk2(f0 * rd, f1 * rd);
            p.y = pk2(f2 * rd, f3 * rd);
            p.z = pk2(f4 * rd, f5 * rd);
            p.w = pk2(f6 * rd, f7 * rd);
            *reinterpret_cast<uint4*>(&A[nl][q * 8]) = p;
        }
    }
    __syncthreads();

    const int r15 = lane & 15, g4 = lane >> 4;
    const int n0 = wid * 32;
    f32x4 acc[2][2] = {};
    for (int kk = 0; kk < 4; ++kk) {
        short8 b0 = *reinterpret_cast<const short8*>(Bp1 + (((kk * 128 + n0 + r15) * 4 + g4) << 3));
        short8 b1 = *reinterpret_cast<const short8*>(Bp1 + (((kk * 128 + n0 + 16 + r15) * 4 + g4) << 3));
        #pragma unroll
        for (int mt = 0; mt < 2; ++mt) {
            short8 a = *reinterpret_cast<const short8*>(&A[mt * 16 + r15][kk * 32 + g4 * 8]);
            acc[mt][0] = __builtin_amdgcn_mfma_f32_16x16x32_bf16(a, b0, acc[mt][0], 0, 0, 0);
            acc[mt][1] = __builtin_amdgcn_mfma_f32_16x16x32_bf16(a, b1, acc[mt][1], 0, 0, 0);
        }
    }
    #pragma unroll
    for (int mt = 0; mt < 2; ++mt)
        #pragma unroll
        for (int nt = 0; nt < 2; ++nt) {
            int col = n0 + nt * 16 + r15;
            float bb = b[col];
            #pragma unroll
            for (int reg = 0; reg < 4; ++reg) {
                int row = tile + mt * 16 + g4 * 4 + reg;
                h1h[(size_t)row * 128 + col] = f2bf(fmaxf(acc[mt][nt][reg] + bb, 0.0f));
            }
        }
}

// ================= layer 2 + heads: grouped-x4 gather + MFMA dense + relu + heads =================
// Gather: 4 lane-groups of 16; one dwordx4 wave-load covers 4 edges' 256B rows.
__global__ __launch_bounds__(256, 8) void k_layer2(
    const unsigned int* __restrict__ h1h32,
    const int* __restrict__ rowstart, const int* __restrict__ srcs,
    const unsigned short* __restrict__ Bp2, const float* __restrict__ b,
    const float* __restrict__ Wh, const float* __restrict__ bh,
    const float* __restrict__ Wm, const float* __restrict__ bm,
    float* __restrict__ out1, float* __restrict__ out2)
{
    __shared__ unsigned short A[32][264];
    __shared__ int rs[33];
    const int tile = blockIdx.x * 32;
    const int tid = threadIdx.x, lane = tid & 63, wid = tid >> 6;

    if (tid < 33) rs[tid] = rowstart[tile + tid];
    {   // root rows -> cols 128..255
        int node = tid >> 3, part = tid & 7;
        const unsigned int* p = h1h32 + (((unsigned)(tile + node)) << 6) + part * 8;
        uint4 v0 = *reinterpret_cast<const uint4*>(p);
        uint4 v1 = *reinterpret_cast<const uint4*>(p + 4);
        *reinterpret_cast<uint4*>(&A[node][128 + part * 16]) = v0;
        *reinterpret_cast<uint4*>(&A[node][128 + part * 16 + 8]) = v1;
    }
    __syncthreads();

    const int g = lane >> 4;                    // edge group 0..3
    const int q = lane & 15;                    // 16B chunk -> features 8q..8q+7
    for (int it = 0; it < 8; ++it) {
        int nl = wid * 8 + it;
        int e0 = rs[nl], e1 = rs[nl + 1];
        float f0 = 0.f, f1 = 0.f, f2 = 0.f, f3 = 0.f, f4 = 0.f, f5 = 0.f, f6 = 0.f, f7 = 0.f;
        int e = e0;
        for (; e + 4 <= e1; e += 4) {
            int s = srcs[e + g];
            uint4 u = *reinterpret_cast<const uint4*>(h1h32 + (((unsigned)s) << 6) + q * 4);
            f0 += bflo(u.x); f1 += bfhi(u.x);
            f2 += bflo(u.y); f3 += bfhi(u.y);
            f4 += bflo(u.z); f5 += bfhi(u.z);
            f6 += bflo(u.w); f7 += bfhi(u.w);
        }
        for (; e < e1; ++e) {
            if (g == 0) {
                uint4 u = *reinterpret_cast<const uint4*>(h1h32 + (((unsigned)srcs[e]) << 6) + q * 4);
                f0 += bflo(u.x); f1 += bfhi(u.x);
                f2 += bflo(u.y); f3 += bfhi(u.y);
                f4 += bflo(u.z); f5 += bfhi(u.z);
                f6 += bflo(u.w); f7 += bfhi(u.w);
            }
        }
        // reduce across 4 edge-groups
        f0 += __shfl_xor(f0, 16); f0 += __shfl_xor(f0, 32);
        f1 += __shfl_xor(f1, 16); f1 += __shfl_xor(f1, 32);
        f2 += __shfl_xor(f2, 16); f2 += __shfl_xor(f2, 32);
        f3 += __shfl_xor(f3, 16); f3 += __shfl_xor(f3, 32);
        f4 += __shfl_xor(f4, 16); f4 += __shfl_xor(f4, 32);
        f5 += __shfl_xor(f5, 16); f5 += __shfl_xor(f5, 32);
        f6 += __shfl_xor(f6, 16); f6 += __shfl_xor(f6, 32);
        f7 += __shfl_xor(f7, 16); f7 += __shfl_xor(f7, 32);
        int d = e1 - e0;
        float rd = (d > 0) ? (1.0f / (float)d) : 1.0f;
        if (g == 0) {
            uint4 p;
            p.x = pk2(f0 * rd, f1 * rd);
            p.y = pk2(f2 * rd, f3 * rd);
            p.z = pk2(f4 * rd, f5 * rd);
            p.w = pk2(f6 * rd, f7 * rd);
            *reinterpret_cast<uint4*>(&A[nl][q * 8]) = p;
        }
    }
    __syncthreads();

    const int r15 = lane & 15, g4 = lane >> 4;
    const int n0 = wid * 32;
    f32x4 acc[2][2] = {};
    for (int kk = 0; kk < 8; ++kk) {
        short8 b0 = *reinterpret_cast<const short8*>(Bp2 + (((kk * 128 + n0 + r15) * 4 + g4) << 3));
        short8 b1 = *reinterpret_cast<const short8*>(Bp2 + (((kk * 128 + n0 + 16 + r15) * 4 + g4) << 3));
        #pragma unroll
        for (int mt = 0; mt < 2; ++mt) {
            short8 a = *reinterpret_cast<const short8*>(&A[mt * 16 + r15][kk * 32 + g4 * 8]);
            acc[mt][0] = __builtin_amdgcn_mfma_f32_16x16x32_bf16(a, b0, acc[mt][0], 0, 0, 0);
            acc[mt][1] = __builtin_amdgcn_mfma_f32_16x16x32_bf16(a, b1, acc[mt][1], 0, 0, 0);
        }
    }
    __syncthreads();
    float* h2L = reinterpret_cast<float*>(&A[0][0]);   // [32][132]
    #pragma unroll
    for (int mt = 0; mt < 2; ++mt)
        #pragma unroll
        for (int nt = 0; nt < 2; ++nt) {
            int col = n0 + nt * 16 + r15;
            float bb = b[col];
            #pragma unroll
            for (int reg = 0; reg < 4; ++reg) {
                int row = mt * 16 + g4 * 4 + reg;
                h2L[row * 132 + col] = fmaxf(acc[mt][nt][reg] + bb, 0.0f);
            }
        }
    __syncthreads();

    for (int t = tid; t < 352; t += 256) {       // heads
        int node = t / 11, o = t - node * 11;
        const float* h2 = &h2L[node * 132];
        if (o < 3) {
            float s = bh[o];
            for (int k = 0; k < 128; ++k) s += h2[k] * Wh[k * 3 + o];
            out1[(size_t)(tile + node) * 3 + o] = s;
        } else {
            int m = o - 3;
            float s = bm[m];
            for (int k = 0; k < 128; ++k) s += h2[k] * Wm[k * 8 + m];
            out2[(size_t)(tile + node) * 8 + m] = s;
        }
    }
}

extern "C" void kernel_launch(void* const* d_in, const int* in_sizes, int n_in,
                              void* d_out, int out_size, void* d_ws, size_t ws_size,
                              hipStream_t stream) {
    const float* x   = (const float*)d_in[0];
    const int*   ei  = (const int*)d_in[1];
    const int*   src = ei;
    const int*   dst = ei + N_EDGES;
    const float* Wl1 = (const float*)d_in[2];
    const float* Wr1 = (const float*)d_in[3];
    const float* b1  = (const float*)d_in[4];
    const float* Wl2 = (const float*)d_in[5];
    const float* Wr2 = (const float*)d_in[6];
    const float* b2  = (const float*)d_in[7];
    const float* Wh  = (const float*)d_in[8];
    const float* bh  = (const float*)d_in[9];
    const float* Wm  = (const float*)d_in[10];
    const float* bm  = (const float*)d_in[11];

    float* out1 = (float*)d_out;                   // [N,3]
    float* out2 = out1 + (size_t)N_NODES * 3;      // [N,8]

    char* ws = (char*)d_ws;
    int*   deg      = (int*)(ws);                           // 100000 ints
    int*   rowstart = (int*)(ws + (512 << 10));             // 100001 ints
    int*   bsum     = (int*)(ws + (960 << 10));             // 98 ints
    int*   boff     = (int*)(ws + (1024 << 10));            // 98 ints
    int*   ccur     = (int*)(ws + (1088 << 10));            // 196 ints
    unsigned int* pairs = (unsigned int*)(ws + (1536 << 10)); // 1.6M u32 (6.4MB)
    int*   srcs     = (int*)(ws + (8192 << 10));            // 1.6M ints (6.4MB)
    unsigned short* xh  = (unsigned short*)(ws + (15360 << 10)); // 6.4M bf16 (12.8MB)
    unsigned short* h1h = (unsigned short*)(ws + (28672 << 10)); // 12.8M bf16 (25.6MB)
    unsigned short* Bp1 = (unsigned short*)(ws + (54784 << 10)); // 16384 bf16 (32KB)
    unsigned short* Bp2 = (unsigned short*)(ws + (54848 << 10)); // 32768 bf16 (64KB)

    const int NSCAN = (N_NODES + 1023) / 1024;              // 98
    const int NBKT_BLKS = (N_EDGES + 256 * EPT - 1) / (256 * EPT);  // 391

    hipMemsetAsync(deg, 0, N_NODES * sizeof(int), stream);
    k_cast_hist<<<6250, 256, 0, stream>>>(x, xh, dst, deg);
    k_part_scan<<<NSCAN, 1024, 0, stream>>>(deg, rowstart, bsum);
    k_scan_bsum<<<1, 128, 0, stream>>>(bsum, boff, rowstart, ccur, NSCAN);
    k_add_off<<<NSCAN, 1024, 0, stream>>>(boff, rowstart);
    k_bucket<<<NBKT_BLKS, 256, 0, stream>>>(src, dst, ccur, pairs);
    k_scatter_csr<<<NBUCK, 256, 0, stream>>>(rowstart, pairs, srcs);
    k_pack<<<192, 256, 0, stream>>>(Wl1, Wr1, Wl2, Wr2, Bp1, Bp2);

    k_layer1<<<3125, 256, 0, stream>>>(xh, rowstart, srcs, Bp1, b1, h1h);
    k_layer2<<<3125, 256, 0, stream>>>((const unsigned int*)h1h, rowstart, srcs,
                                       Bp2, b2, Wh, bh, Wm, bm, out1, out2);
}

// Round 10
// 317.495 us; speedup vs baseline: 1.0336x; 1.0336x over previous
//
#include <hip/hip_runtime.h>

#define N_NODES 100000
#define N_EDGES 1600000
#define NBUCK 391      // ceil(100000/256) coarse buckets
#define BSH 8          // 256 nodes per bucket
#define EPT 32         // edges per thread in k_bucket

typedef __attribute__((ext_vector_type(8))) short short8;
typedef __attribute__((ext_vector_type(4))) float f32x4;

__device__ __forceinline__ float bflo(unsigned int u) { return __uint_as_float(u << 16); }
__device__ __forceinline__ float bfhi(unsigned int u) { return __uint_as_float(u & 0xffff0000u); }
__device__ __forceinline__ float bf2f(unsigned short u) { return __uint_as_float(((unsigned int)u) << 16); }
__device__ __forceinline__ unsigned short f2bf(float f) {
    unsigned int u = __float_as_uint(f);
    return (unsigned short)((u + 0x7fffu + ((u >> 16) & 1u)) >> 16);   // RNE
}

// ================= fused: cast x->bf16 + degree histogram + weight prepack =================
__global__ __launch_bounds__(256) void k_cast_hist_pack(
    const float* __restrict__ x, unsigned short* __restrict__ xh,
    const int* __restrict__ dst, int* __restrict__ deg,
    const float* __restrict__ Wl1, const float* __restrict__ Wr1,
    const float* __restrict__ Wl2, const float* __restrict__ Wr2,
    unsigned short* __restrict__ Bp1, unsigned short* __restrict__ Bp2)
{
    if (blockIdx.x < 6250) {
        int i = blockIdx.x * 256 + threadIdx.x;     // 1.6M threads: 4 x-elems + 1 edge each
        float4 v = *reinterpret_cast<const float4*>(x + (size_t)i * 4);
        ushort4 o;
        o.x = f2bf(v.x); o.y = f2bf(v.y); o.z = f2bf(v.z); o.w = f2bf(v.w);
        *reinterpret_cast<ushort4*>(xh + (size_t)i * 4) = o;
        atomicAdd(&deg[dst[i]], 1);
    } else {
        int idx = (blockIdx.x - 6250) * 256 + threadIdx.x;   // 49152 pack threads
        if (idx < 16384) {                          // layer1: K=128
            int j = idx & 7, g = (idx >> 3) & 3, col = (idx >> 5) & 127, kk = idx >> 12;
            int r = kk * 32 + g * 8 + j;
            float w = (r < 64) ? Wl1[r * 128 + col] : Wr1[(r - 64) * 128 + col];
            Bp1[idx] = f2bf(w);
        } else {                                    // layer2: K=256
            int q = idx - 16384;
            int j = q & 7, g = (q >> 3) & 3, col = (q >> 5) & 127, kk = q >> 12;
            int r = kk * 32 + g * 8 + j;
            float w = (r < 128) ? Wl2[r * 128 + col] : Wr2[(r - 128) * 128 + col];
            Bp2[q] = f2bf(w);
        }
    }
}

// ================= CSR scan chain =================
__global__ __launch_bounds__(1024) void k_part_scan(const int* __restrict__ deg,
                                                    int* __restrict__ rowstart, int* __restrict__ bsum) {
    __shared__ int wsum[16];
    const int tid = threadIdx.x, lane = tid & 63, wid = tid >> 6;
    int i = blockIdx.x * 1024 + tid;
    int v = (i < N_NODES) ? deg[i] : 0;
    int s = v;
    #pragma unroll
    for (int off = 1; off < 64; off <<= 1) {
        int t = __shfl_up(s, off);
        if (lane >= off) s += t;
    }
    if (lane == 63) wsum[wid] = s;
    __syncthreads();
    if (tid < 16) {
        int w = wsum[tid];
        #pragma unroll
        for (int off = 1; off < 16; off <<= 1) {
            int t = __shfl_up(w, off);
            if (tid >= off) w += t;
        }
        wsum[tid] = w;
    }
    __syncthreads();
    int wexcl = (wid == 0) ? 0 : wsum[wid - 1];
    if (i < N_NODES) rowstart[i] = wexcl + s - v;
    if (tid == 1023) bsum[blockIdx.x] = wexcl + s;
}

// scan of 98 block sums; writes rowstart[N]; initializes bucket cursors to FINAL rowstart
__global__ __launch_bounds__(128) void k_scan_bsum(const int* __restrict__ bsum, int* __restrict__ boff,
                                                   int* __restrict__ rowstart, int* __restrict__ ccur, int nblk) {
    __shared__ int sh[128];
    __shared__ int excl[128];
    int t = threadIdx.x;
    int v = (t < nblk) ? bsum[t] : 0;
    int acc = v;
    sh[t] = acc;
    __syncthreads();
    #pragma unroll
    for (int off = 1; off < 128; off <<= 1) {
        int add = (t >= off) ? sh[t - off] : 0;
        __syncthreads();
        acc += add;
        sh[t] = acc;
        __syncthreads();
    }
    if (t < nblk) boff[t] = acc - v;
    excl[t] = acc - v;
    if (t == nblk - 1) rowstart[N_NODES] = acc;
    __syncthreads();
    for (int c = t; c < NBUCK; c += 128)   // bucket start node = c<<8; its scan block = c>>2
        ccur[c] = rowstart[c << BSH] + excl[c >> 2];
}

__global__ __launch_bounds__(1024) void k_add_off(const int* __restrict__ boff, int* __restrict__ rowstart) {
    int i = blockIdx.x * 1024 + threadIdx.x;
    if (i < N_NODES) rowstart[i] += boff[blockIdx.x];
}

// ================= CSR build pass 1: coarse bucket (counting sort, packed pairs) =================
__global__ __launch_bounds__(256) void k_bucket(const int* __restrict__ src, const int* __restrict__ dst,
                                                int* __restrict__ ccur, unsigned int* __restrict__ pairs) {
    __shared__ int cnt[NBUCK];
    __shared__ int base[NBUCK];
    const int tid = threadIdx.x;
    const int e_base = blockIdx.x * (256 * EPT);
    for (int i = tid; i < NBUCK; i += 256) cnt[i] = 0;
    __syncthreads();
    #pragma unroll
    for (int i = 0; i < EPT; ++i) {              // phase A: local histogram
        int e = e_base + i * 256 + tid;
        if (e < N_EDGES) atomicAdd(&cnt[dst[e] >> BSH], 1);
    }
    __syncthreads();
    for (int i = tid; i < NBUCK; i += 256) {     // phase B: reserve global ranges
        int c = cnt[i];
        base[i] = (c > 0) ? atomicAdd(&ccur[i], c) : 0;
        cnt[i] = 0;
    }
    __syncthreads();
    #pragma unroll
    for (int i = 0; i < EPT; ++i) {              // phase C: grouped scatter
        int e = e_base + i * 256 + tid;
        if (e < N_EDGES) {
            int d = dst[e];
            int bkt = d >> BSH;
            int off = atomicAdd(&cnt[bkt], 1);
            pairs[base[bkt] + off] = ((unsigned int)(d & 255) << 17) | (unsigned int)src[e];
        }
    }
}

// ================= CSR build pass 2: within-bucket exact scatter (LDS cursors) =================
__global__ __launch_bounds__(256) void k_scatter_csr(const int* __restrict__ rowstart,
                                                     const unsigned int* __restrict__ pairs,
                                                     int* __restrict__ srcs) {
    __shared__ int lcur[256];
    const int c = blockIdx.x, tid = threadIdx.x;
    const int nbase = c << BSH;
    {
        int n = nbase + tid;
        lcur[tid] = (n < N_NODES) ? rowstart[n] : 0;
    }
    __syncthreads();
    int e0 = rowstart[nbase];
    int nend = nbase + 256; if (nend > N_NODES) nend = N_NODES;
    int e1 = rowstart[nend];
    for (int e = e0 + tid; e < e1; e += 256) {
        unsigned int u = pairs[e];
        int dloc = (int)(u >> 17);
        int p = atomicAdd(&lcur[dloc], 1);
        srcs[p] = (int)(u & 0x1FFFFu);
    }
}

// ================= layer 1: gather(bf16, unroll-8) + MFMA dense + relu -> bf16 h1h =================
__global__ __launch_bounds__(256, 8) void k_layer1(
    const unsigned short* __restrict__ xh,
    const int* __restrict__ rowstart, const int* __restrict__ srcs,
    const unsigned short* __restrict__ Bp1, const float* __restrict__ b,
    unsigned short* __restrict__ h1h)
{
    __shared__ unsigned short A[32][136];
    __shared__ int rs[33];
    const int tile = blockIdx.x * 32;           // 100000 = 3125*32
    const int tid = threadIdx.x, lane = tid & 63, wid = tid >> 6;

    if (tid < 33) rs[tid] = rowstart[tile + tid];
    {   // root rows -> cols 64..127
        int node = tid >> 3, part = tid & 7;
        uint4 v = *reinterpret_cast<const uint4*>(xh + (size_t)(tile + node) * 64 + part * 8);
        *reinterpret_cast<uint4*>(&A[node][64 + part * 8]) = v;
    }
    __syncthreads();

    for (int it = 0; it < 8; ++it) {            // wave-per-node gather, unroll-8
        int nl = wid * 8 + it;
        int e0 = rs[nl], e1 = rs[nl + 1];
        float a0 = 0.f, a1 = 0.f, a2 = 0.f, a3 = 0.f;
        int e = e0;
        for (; e + 8 <= e1; e += 8) {
            int s0 = srcs[e],     s1 = srcs[e + 1], s2 = srcs[e + 2], s3 = srcs[e + 3];
            int s4 = srcs[e + 4], s5 = srcs[e + 5], s6 = srcs[e + 6], s7 = srcs[e + 7];
            float v0 = bf2f(xh[(size_t)s0 * 64 + lane]);
            float v1 = bf2f(xh[(size_t)s1 * 64 + lane]);
            float v2 = bf2f(xh[(size_t)s2 * 64 + lane]);
            float v3 = bf2f(xh[(size_t)s3 * 64 + lane]);
            float v4 = bf2f(xh[(size_t)s4 * 64 + lane]);
            float v5 = bf2f(xh[(size_t)s5 * 64 + lane]);
            float v6 = bf2f(xh[(size_t)s6 * 64 + lane]);
            float v7 = bf2f(xh[(size_t)s7 * 64 + lane]);
            a0 += v0; a1 += v1; a2 += v2; a3 += v3;
            a0 += v4; a1 += v5; a2 += v6; a3 += v7;
        }
        for (; e < e1; ++e)
            a0 += bf2f(xh[(size_t)srcs[e] * 64 + lane]);
        float acc = (a0 + a1) + (a2 + a3);
        int d = e1 - e0;
        A[nl][lane] = f2bf(acc * ((d > 0) ? (1.0f / (float)d) : 1.0f));
    }
    __syncthreads();

    const int r15 = lane & 15, g4 = lane >> 4;
    const int n0 = wid * 32;
    f32x4 acc[2][2] = {};
    for (int kk = 0; kk < 4; ++kk) {
        short8 b0 = *reinterpret_cast<const short8*>(Bp1 + (((kk * 128 + n0 + r15) * 4 + g4) << 3));
        short8 b1 = *reinterpret_cast<const short8*>(Bp1 + (((kk * 128 + n0 + 16 + r15) * 4 + g4) << 3));
        #pragma unroll
        for (int mt = 0; mt < 2; ++mt) {
            short8 a = *reinterpret_cast<const short8*>(&A[mt * 16 + r15][kk * 32 + g4 * 8]);
            acc[mt][0] = __builtin_amdgcn_mfma_f32_16x16x32_bf16(a, b0, acc[mt][0], 0, 0, 0);
            acc[mt][1] = __builtin_amdgcn_mfma_f32_16x16x32_bf16(a, b1, acc[mt][1], 0, 0, 0);
        }
    }
    #pragma unroll
    for (int mt = 0; mt < 2; ++mt)
        #pragma unroll
        for (int nt = 0; nt < 2; ++nt) {
            int col = n0 + nt * 16 + r15;
            float bb = b[col];
            #pragma unroll
            for (int reg = 0; reg < 4; ++reg) {
                int row = tile + mt * 16 + g4 * 4 + reg;
                h1h[(size_t)row * 128 + col] = f2bf(fmaxf(acc[mt][nt][reg] + bb, 0.0f));
            }
        }
}

// ================= layer 2 + heads: gather(bf16x2, unroll-8) + MFMA dense + relu + heads =================
__global__ __launch_bounds__(256, 8) void k_layer2(
    const unsigned int* __restrict__ h1h32,
    const int* __restrict__ rowstart, const int* __restrict__ srcs,
    const unsigned short* __restrict__ Bp2, const float* __restrict__ b,
    const float* __restrict__ Wh, const float* __restrict__ bh,
    const float* __restrict__ Wm, const float* __restrict__ bm,
    float* __restrict__ out1, float* __restrict__ out2)
{
    __shared__ unsigned short A[32][264];
    __shared__ int rs[33];
    const int tile = blockIdx.x * 32;
    const int tid = threadIdx.x, lane = tid & 63, wid = tid >> 6;

    if (tid < 33) rs[tid] = rowstart[tile + tid];
    {   // root rows -> cols 128..255
        int node = tid >> 3, part = tid & 7;
        const unsigned int* p = h1h32 + (size_t)(tile + node) * 64 + part * 8;
        uint4 v0 = *reinterpret_cast<const uint4*>(p);
        uint4 v1 = *reinterpret_cast<const uint4*>(p + 4);
        *reinterpret_cast<uint4*>(&A[node][128 + part * 16]) = v0;
        *reinterpret_cast<uint4*>(&A[node][128 + part * 16 + 8]) = v1;
    }
    __syncthreads();

    for (int it = 0; it < 8; ++it) {            // wave-per-node gather, unroll-8
        int nl = wid * 8 + it;
        int e0 = rs[nl], e1 = rs[nl + 1];
        float ax0 = 0.f, ax1 = 0.f, ax2 = 0.f, ax3 = 0.f;
        float ay0 = 0.f, ay1 = 0.f, ay2 = 0.f, ay3 = 0.f;
        int e = e0;
        for (; e + 8 <= e1; e += 8) {
            int s0 = srcs[e],     s1 = srcs[e + 1], s2 = srcs[e + 2], s3 = srcs[e + 3];
            int s4 = srcs[e + 4], s5 = srcs[e + 5], s6 = srcs[e + 6], s7 = srcs[e + 7];
            unsigned int u0 = h1h32[(size_t)s0 * 64 + lane];
            unsigned int u1 = h1h32[(size_t)s1 * 64 + lane];
            unsigned int u2 = h1h32[(size_t)s2 * 64 + lane];
            unsigned int u3 = h1h32[(size_t)s3 * 64 + lane];
            unsigned int u4 = h1h32[(size_t)s4 * 64 + lane];
            unsigned int u5 = h1h32[(size_t)s5 * 64 + lane];
            unsigned int u6 = h1h32[(size_t)s6 * 64 + lane];
            unsigned int u7 = h1h32[(size_t)s7 * 64 + lane];
            ax0 += bflo(u0); ay0 += bfhi(u0);
            ax1 += bflo(u1); ay1 += bfhi(u1);
            ax2 += bflo(u2); ay2 += bfhi(u2);
            ax3 += bflo(u3); ay3 += bfhi(u3);
            ax0 += bflo(u4); ay0 += bfhi(u4);
            ax1 += bflo(u5); ay1 += bfhi(u5);
            ax2 += bflo(u6); ay2 += bfhi(u6);
            ax3 += bflo(u7); ay3 += bfhi(u7);
        }
        for (; e < e1; ++e) {
            unsigned int u = h1h32[(size_t)srcs[e] * 64 + lane];
            ax0 += bflo(u); ay0 += bfhi(u);
        }
        float ax = (ax0 + ax1) + (ax2 + ax3);
        float ay = (ay0 + ay1) + (ay2 + ay3);
        int d = e1 - e0;
        float rd = (d > 0) ? (1.0f / (float)d) : 1.0f;
        unsigned int p = (unsigned int)f2bf(ax * rd) | ((unsigned int)f2bf(ay * rd) << 16);
        *reinterpret_cast<unsigned int*>(&A[nl][2 * lane]) = p;
    }
    __syncthreads();

    const int r15 = lane & 15, g4 = lane >> 4;
    const int n0 = wid * 32;
    f32x4 acc[2][2] = {};
    for (int kk = 0; kk < 8; ++kk) {
        short8 b0 = *reinterpret_cast<const short8*>(Bp2 + (((kk * 128 + n0 + r15) * 4 + g4) << 3));
        short8 b1 = *reinterpret_cast<const short8*>(Bp2 + (((kk * 128 + n0 + 16 + r15) * 4 + g4) << 3));
        #pragma unroll
        for (int mt = 0; mt < 2; ++mt) {
            short8 a = *reinterpret_cast<const short8*>(&A[mt * 16 + r15][kk * 32 + g4 * 8]);
            acc[mt][0] = __builtin_amdgcn_mfma_f32_16x16x32_bf16(a, b0, acc[mt][0], 0, 0, 0);
            acc[mt][1] = __builtin_amdgcn_mfma_f32_16x16x32_bf16(a, b1, acc[mt][1], 0, 0, 0);
        }
    }
    __syncthreads();
    float* h2L = reinterpret_cast<float*>(&A[0][0]);   // [32][132]
    #pragma unroll
    for (int mt = 0; mt < 2; ++mt)
        #pragma unroll
        for (int nt = 0; nt < 2; ++nt) {
            int col = n0 + nt * 16 + r15;
            float bb = b[col];
            #pragma unroll
            for (int reg = 0; reg < 4; ++reg) {
                int row = mt * 16 + g4 * 4 + reg;
                h2L[row * 132 + col] = fmaxf(acc[mt][nt][reg] + bb, 0.0f);
            }
        }
    __syncthreads();

    for (int t = tid; t < 352; t += 256) {       // heads
        int node = t / 11, o = t - node * 11;
        const float* h2 = &h2L[node * 132];
        if (o < 3) {
            float s = bh[o];
            for (int k = 0; k < 128; ++k) s += h2[k] * Wh[k * 3 + o];
            out1[(size_t)(tile + node) * 3 + o] = s;
        } else {
            int m = o - 3;
            float s = bm[m];
            for (int k = 0; k < 128; ++k) s += h2[k] * Wm[k * 8 + m];
            out2[(size_t)(tile + node) * 8 + m] = s;
        }
    }
}

extern "C" void kernel_launch(void* const* d_in, const int* in_sizes, int n_in,
                              void* d_out, int out_size, void* d_ws, size_t ws_size,
                              hipStream_t stream) {
    const float* x   = (const float*)d_in[0];
    const int*   ei  = (const int*)d_in[1];
    const int*   src = ei;
    const int*   dst = ei + N_EDGES;
    const float* Wl1 = (const float*)d_in[2];
    const float* Wr1 = (const float*)d_in[3];
    const float* b1  = (const float*)d_in[4];
    const float* Wl2 = (const float*)d_in[5];
    const float* Wr2 = (const float*)d_in[6];
    const float* b2  = (const float*)d_in[7];
    const float* Wh  = (const float*)d_in[8];
    const float* bh  = (const float*)d_in[9];
    const float* Wm  = (const float*)d_in[10];
    const float* bm  = (const float*)d_in[11];

    float* out1 = (float*)d_out;                   // [N,3]
    float* out2 = out1 + (size_t)N_NODES * 3;      // [N,8]

    char* ws = (char*)d_ws;
    int*   deg      = (int*)(ws);                           // 100000 ints
    int*   rowstart = (int*)(ws + (512 << 10));             // 100001 ints
    int*   bsum     = (int*)(ws + (960 << 10));             // 98 ints
    int*   boff     = (int*)(ws + (1024 << 10));            // 98 ints
    int*   ccur     = (int*)(ws + (1088 << 10));            // 391 ints
    unsigned int* pairs = (unsigned int*)(ws + (1536 << 10)); // 1.6M u32 (6.4MB)
    int*   srcs     = (int*)(ws + (8192 << 10));            // 1.6M ints (6.4MB)
    unsigned short* xh  = (unsigned short*)(ws + (15360 << 10)); // 6.4M bf16 (12.8MB)
    unsigned short* h1h = (unsigned short*)(ws + (28672 << 10)); // 12.8M bf16 (25.6MB)
    unsigned short* Bp1 = (unsigned short*)(ws + (54784 << 10)); // 16384 bf16 (32KB)
    unsigned short* Bp2 = (unsigned short*)(ws + (54848 << 10)); // 32768 bf16 (64KB)

    const int NSCAN = (N_NODES + 1023) / 1024;              // 98
    const int NBKT_BLKS = (N_EDGES + 256 * EPT - 1) / (256 * EPT);  // 196

    hipMemsetAsync(deg, 0, N_NODES * sizeof(int), stream);
    k_cast_hist_pack<<<6442, 256, 0, stream>>>(x, xh, dst, deg, Wl1, Wr1, Wl2, Wr2, Bp1, Bp2);
    k_part_scan<<<NSCAN, 1024, 0, stream>>>(deg, rowstart, bsum);
    k_scan_bsum<<<1, 128, 0, stream>>>(bsum, boff, rowstart, ccur, NSCAN);
    k_add_off<<<NSCAN, 1024, 0, stream>>>(boff, rowstart);
    k_bucket<<<NBKT_BLKS, 256, 0, stream>>>(src, dst, ccur, pairs);
    k_scatter_csr<<<NBUCK, 256, 0, stream>>>(rowstart, pairs, srcs);

    k_layer1<<<3125, 256, 0, stream>>>(xh, rowstart, srcs, Bp1, b1, h1h);
    k_layer2<<<3125, 256, 0, stream>>>((const unsigned int*)h1h, rowstart, srcs,
                                       Bp2, b2, Wh, bh, Wm, bm, out1, out2);
}

// Round 11
// 301.568 us; speedup vs baseline: 1.0881x; 1.0528x over previous
//
#include <hip/hip_runtime.h>

#define N_NODES 100000
#define N_EDGES 1600000
#define NBUCK 391      // ceil(100000/256) coarse buckets
#define BSH 8          // 256 nodes per bucket
#define EPT 64         // edges per thread-block-slot in k_bucket (16384 edges/block, 98 blocks)

typedef __attribute__((ext_vector_type(8))) short short8;
typedef __attribute__((ext_vector_type(4))) float f32x4;

__device__ __forceinline__ float bflo(unsigned int u) { return __uint_as_float(u << 16); }
__device__ __forceinline__ float bfhi(unsigned int u) { return __uint_as_float(u & 0xffff0000u); }
__device__ __forceinline__ float bf2f(unsigned short u) { return __uint_as_float(((unsigned int)u) << 16); }
__device__ __forceinline__ unsigned short f2bf(float f) {
    unsigned int u = __float_as_uint(f);
    return (unsigned short)((u + 0x7fffu + ((u >> 16) & 1u)) >> 16);   // RNE
}

// ================= fused: cast x->bf16 | coarse bucket histogram | weight prepack =================
__global__ __launch_bounds__(256) void k_pre(
    const float* __restrict__ x, unsigned short* __restrict__ xh,
    const int* __restrict__ dst, int* __restrict__ bcnt,
    const float* __restrict__ Wl1, const float* __restrict__ Wr1,
    const float* __restrict__ Wl2, const float* __restrict__ Wr2,
    unsigned short* __restrict__ Bp1, unsigned short* __restrict__ Bp2)
{
    __shared__ int hcnt[NBUCK];
    const int tid = threadIdx.x;
    if (blockIdx.x < 6250) {                        // ---- cast x (1.6M threads x 4 floats)
        int i = blockIdx.x * 256 + tid;
        float4 v = *reinterpret_cast<const float4*>(x + (size_t)i * 4);
        ushort4 o;
        o.x = f2bf(v.x); o.y = f2bf(v.y); o.z = f2bf(v.z); o.w = f2bf(v.w);
        *reinterpret_cast<ushort4*>(xh + (size_t)i * 4) = o;
    } else if (blockIdx.x < 6348) {                 // ---- coarse histogram (98 blocks x 16384 edges)
        int blk = blockIdx.x - 6250;
        int e_base = blk * (256 * EPT);
        for (int i = tid; i < NBUCK; i += 256) hcnt[i] = 0;
        __syncthreads();
        #pragma unroll
        for (int i = 0; i < EPT; ++i) {
            int e = e_base + i * 256 + tid;
            if (e < N_EDGES) atomicAdd(&hcnt[dst[e] >> BSH], 1);
        }
        __syncthreads();
        for (int i = tid; i < NBUCK; i += 256) {
            int c = hcnt[i];
            if (c > 0) atomicAdd(&bcnt[i], c);
        }
    } else {                                        // ---- weight prepack (192 blocks)
        int idx = (blockIdx.x - 6348) * 256 + tid;
        if (idx < 16384) {                          // layer1: K=128
            int j = idx & 7, g = (idx >> 3) & 3, col = (idx >> 5) & 127, kk = idx >> 12;
            int r = kk * 32 + g * 8 + j;
            float w = (r < 64) ? Wl1[r * 128 + col] : Wr1[(r - 64) * 128 + col];
            Bp1[idx] = f2bf(w);
        } else {                                    // layer2: K=256
            int q = idx - 16384;
            int j = q & 7, g = (q >> 3) & 3, col = (q >> 5) & 127, kk = q >> 12;
            int r = kk * 32 + g * 8 + j;
            float w = (r < 128) ? Wl2[r * 128 + col] : Wr2[(r - 128) * 128 + col];
            Bp2[q] = f2bf(w);
        }
    }
}

// ================= scan 391 bucket counts -> bbase[392], init ccur =================
__global__ __launch_bounds__(512) void k_scan391(const int* __restrict__ bcnt,
                                                 int* __restrict__ bbase, int* __restrict__ ccur) {
    __shared__ int wsum[8];
    const int tid = threadIdx.x, lane = tid & 63, wid = tid >> 6;
    int v = (tid < NBUCK) ? bcnt[tid] : 0;
    int s = v;
    #pragma unroll
    for (int off = 1; off < 64; off <<= 1) {
        int t = __shfl_up(s, off);
        if (lane >= off) s += t;
    }
    if (lane == 63) wsum[wid] = s;
    __syncthreads();
    if (tid < 8) {
        int w = wsum[tid];
        #pragma unroll
        for (int off = 1; off < 8; off <<= 1) {
            int t = __shfl_up(w, off);
            if (tid >= off) w += t;
        }
        wsum[tid] = w;
    }
    __syncthreads();
    int excl = ((wid == 0) ? 0 : wsum[wid - 1]) + s - v;
    if (tid < NBUCK + 1) bbase[tid] = excl;
    if (tid < NBUCK) ccur[tid] = excl;
}

// ================= CSR pass 1: coarse counting-sort into packed pairs =================
__global__ __launch_bounds__(256) void k_bucket(const int* __restrict__ src, const int* __restrict__ dst,
                                                int* __restrict__ ccur, unsigned int* __restrict__ pairs) {
    __shared__ int cnt[NBUCK];
    __shared__ int base[NBUCK];
    const int tid = threadIdx.x;
    const int e_base = blockIdx.x * (256 * EPT);
    for (int i = tid; i < NBUCK; i += 256) cnt[i] = 0;
    __syncthreads();
    #pragma unroll
    for (int i = 0; i < EPT; ++i) {              // phase A: local histogram
        int e = e_base + i * 256 + tid;
        if (e < N_EDGES) atomicAdd(&cnt[dst[e] >> BSH], 1);
    }
    __syncthreads();
    for (int i = tid; i < NBUCK; i += 256) {     // phase B: reserve global ranges
        int c = cnt[i];
        base[i] = (c > 0) ? atomicAdd(&ccur[i], c) : 0;
        cnt[i] = 0;
    }
    __syncthreads();
    #pragma unroll
    for (int i = 0; i < EPT; ++i) {              // phase C: grouped scatter
        int e = e_base + i * 256 + tid;
        if (e < N_EDGES) {
            int d = dst[e];
            int bkt = d >> BSH;
            int off = atomicAdd(&cnt[bkt], 1);
            pairs[base[bkt] + off] = ((unsigned int)(d & 255) << 17) | (unsigned int)src[e];
        }
    }
}

// ================= CSR pass 2: per-bucket local hist + scan -> rowstart; exact scatter =================
__global__ __launch_bounds__(256) void k_csr(const int* __restrict__ bbase,
                                             const unsigned int* __restrict__ pairs,
                                             int* __restrict__ rowstart, int* __restrict__ srcs) {
    __shared__ int nh[256];       // per-node counts -> cursors
    __shared__ int wsum[4];
    const int c = blockIdx.x, tid = threadIdx.x, lane = tid & 63, wid = tid >> 6;
    const int nbase = c << BSH;
    const int e0 = bbase[c], e1 = bbase[c + 1];

    nh[tid] = 0;
    __syncthreads();
    for (int e = e0 + tid; e < e1; e += 256)     // phase A: node histogram from pairs
        atomicAdd(&nh[pairs[e] >> 17], 1);
    __syncthreads();
    int v = nh[tid];                              // phase B: scan 256 counts
    int s = v;
    #pragma unroll
    for (int off = 1; off < 64; off <<= 1) {
        int t = __shfl_up(s, off);
        if (lane >= off) s += t;
    }
    if (lane == 63) wsum[wid] = s;
    __syncthreads();
    if (tid < 4) {
        int w = wsum[tid];
        #pragma unroll
        for (int off = 1; off < 4; off <<= 1) {
            int t = __shfl_up(w, off);
            if (tid >= off) w += t;
        }
        wsum[tid] = w;
    }
    __syncthreads();
    int excl = e0 + ((wid == 0) ? 0 : wsum[wid - 1]) + s - v;
    int n = nbase + tid;
    if (n < N_NODES) rowstart[n] = excl;          // coalesced rowstart write
    if (c == NBUCK - 1 && tid == 0) rowstart[N_NODES] = bbase[NBUCK];
    __syncthreads();
    nh[tid] = excl;                               // reuse as cursors
    __syncthreads();
    for (int e = e0 + tid; e < e1; e += 256) {    // phase C: exact scatter (LDS cursors)
        unsigned int u = pairs[e];
        int p = atomicAdd(&nh[u >> 17], 1);
        srcs[p] = (int)(u & 0x1FFFFu);
    }
}

// ================= layer 1: gather(bf16, unroll-8) + MFMA dense + relu -> bf16 h1h =================
__global__ __launch_bounds__(256, 8) void k_layer1(
    const unsigned short* __restrict__ xh,
    const int* __restrict__ rowstart, const int* __restrict__ srcs,
    const unsigned short* __restrict__ Bp1, const float* __restrict__ b,
    unsigned short* __restrict__ h1h)
{
    __shared__ unsigned short A[32][136];
    __shared__ int rs[33];
    const int tile = blockIdx.x * 32;           // 100000 = 3125*32
    const int tid = threadIdx.x, lane = tid & 63, wid = tid >> 6;

    if (tid < 33) rs[tid] = rowstart[tile + tid];
    {   // root rows -> cols 64..127
        int node = tid >> 3, part = tid & 7;
        uint4 v = *reinterpret_cast<const uint4*>(xh + (size_t)(tile + node) * 64 + part * 8);
        *reinterpret_cast<uint4*>(&A[node][64 + part * 8]) = v;
    }
    __syncthreads();

    for (int it = 0; it < 8; ++it) {            // wave-per-node gather, unroll-8
        int nl = wid * 8 + it;
        int e0 = rs[nl], e1 = rs[nl + 1];
        float a0 = 0.f, a1 = 0.f, a2 = 0.f, a3 = 0.f;
        int e = e0;
        for (; e + 8 <= e1; e += 8) {
            int s0 = srcs[e],     s1 = srcs[e + 1], s2 = srcs[e + 2], s3 = srcs[e + 3];
            int s4 = srcs[e + 4], s5 = srcs[e + 5], s6 = srcs[e + 6], s7 = srcs[e + 7];
            float v0 = bf2f(xh[(size_t)s0 * 64 + lane]);
            float v1 = bf2f(xh[(size_t)s1 * 64 + lane]);
            float v2 = bf2f(xh[(size_t)s2 * 64 + lane]);
            float v3 = bf2f(xh[(size_t)s3 * 64 + lane]);
            float v4 = bf2f(xh[(size_t)s4 * 64 + lane]);
            float v5 = bf2f(xh[(size_t)s5 * 64 + lane]);
            float v6 = bf2f(xh[(size_t)s6 * 64 + lane]);
            float v7 = bf2f(xh[(size_t)s7 * 64 + lane]);
            a0 += v0; a1 += v1; a2 += v2; a3 += v3;
            a0 += v4; a1 += v5; a2 += v6; a3 += v7;
        }
        for (; e < e1; ++e)
            a0 += bf2f(xh[(size_t)srcs[e] * 64 + lane]);
        float acc = (a0 + a1) + (a2 + a3);
        int d = e1 - e0;
        A[nl][lane] = f2bf(acc * ((d > 0) ? (1.0f / (float)d) : 1.0f));
    }
    __syncthreads();

    const int r15 = lane & 15, g4 = lane >> 4;
    const int n0 = wid * 32;
    f32x4 acc[2][2] = {};
    for (int kk = 0; kk < 4; ++kk) {
        short8 b0 = *reinterpret_cast<const short8*>(Bp1 + (((kk * 128 + n0 + r15) * 4 + g4) << 3));
        short8 b1 = *reinterpret_cast<const short8*>(Bp1 + (((kk * 128 + n0 + 16 + r15) * 4 + g4) << 3));
        #pragma unroll
        for (int mt = 0; mt < 2; ++mt) {
            short8 a = *reinterpret_cast<const short8*>(&A[mt * 16 + r15][kk * 32 + g4 * 8]);
            acc[mt][0] = __builtin_amdgcn_mfma_f32_16x16x32_bf16(a, b0, acc[mt][0], 0, 0, 0);
            acc[mt][1] = __builtin_amdgcn_mfma_f32_16x16x32_bf16(a, b1, acc[mt][1], 0, 0, 0);
        }
    }
    #pragma unroll
    for (int mt = 0; mt < 2; ++mt)
        #pragma unroll
        for (int nt = 0; nt < 2; ++nt) {
            int col = n0 + nt * 16 + r15;
            float bb = b[col];
            #pragma unroll
            for (int reg = 0; reg < 4; ++reg) {
                int row = tile + mt * 16 + g4 * 4 + reg;
                h1h[(size_t)row * 128 + col] = f2bf(fmaxf(acc[mt][nt][reg] + bb, 0.0f));
            }
        }
}

// ================= layer 2 + heads: gather(bf16x2, unroll-8) + MFMA dense + relu + heads =================
__global__ __launch_bounds__(256, 8) void k_layer2(
    const unsigned int* __restrict__ h1h32,
    const int* __restrict__ rowstart, const int* __restrict__ srcs,
    const unsigned short* __restrict__ Bp2, const float* __restrict__ b,
    const float* __restrict__ Wh, const float* __restrict__ bh,
    const float* __restrict__ Wm, const float* __restrict__ bm,
    float* __restrict__ out1, float* __restrict__ out2)
{
    __shared__ unsigned short A[32][264];
    __shared__ int rs[33];
    const int tile = blockIdx.x * 32;
    const int tid = threadIdx.x, lane = tid & 63, wid = tid >> 6;

    if (tid < 33) rs[tid] = rowstart[tile + tid];
    {   // root rows -> cols 128..255
        int node = tid >> 3, part = tid & 7;
        const unsigned int* p = h1h32 + (size_t)(tile + node) * 64 + part * 8;
        uint4 v0 = *reinterpret_cast<const uint4*>(p);
        uint4 v1 = *reinterpret_cast<const uint4*>(p + 4);
        *reinterpret_cast<uint4*>(&A[node][128 + part * 16]) = v0;
        *reinterpret_cast<uint4*>(&A[node][128 + part * 16 + 8]) = v1;
    }
    __syncthreads();

    for (int it = 0; it < 8; ++it) {            // wave-per-node gather, unroll-8
        int nl = wid * 8 + it;
        int e0 = rs[nl], e1 = rs[nl + 1];
        float ax0 = 0.f, ax1 = 0.f, ax2 = 0.f, ax3 = 0.f;
        float ay0 = 0.f, ay1 = 0.f, ay2 = 0.f, ay3 = 0.f;
        int e = e0;
        for (; e + 8 <= e1; e += 8) {
            int s0 = srcs[e],     s1 = srcs[e + 1], s2 = srcs[e + 2], s3 = srcs[e + 3];
            int s4 = srcs[e + 4], s5 = srcs[e + 5], s6 = srcs[e + 6], s7 = srcs[e + 7];
            unsigned int u0 = h1h32[(size_t)s0 * 64 + lane];
            unsigned int u1 = h1h32[(size_t)s1 * 64 + lane];
            unsigned int u2 = h1h32[(size_t)s2 * 64 + lane];
            unsigned int u3 = h1h32[(size_t)s3 * 64 + lane];
            unsigned int u4 = h1h32[(size_t)s4 * 64 + lane];
            unsigned int u5 = h1h32[(size_t)s5 * 64 + lane];
            unsigned int u6 = h1h32[(size_t)s6 * 64 + lane];
            unsigned int u7 = h1h32[(size_t)s7 * 64 + lane];
            ax0 += bflo(u0); ay0 += bfhi(u0);
            ax1 += bflo(u1); ay1 += bfhi(u1);
            ax2 += bflo(u2); ay2 += bfhi(u2);
            ax3 += bflo(u3); ay3 += bfhi(u3);
            ax0 += bflo(u4); ay0 += bfhi(u4);
            ax1 += bflo(u5); ay1 += bfhi(u5);
            ax2 += bflo(u6); ay2 += bfhi(u6);
            ax3 += bflo(u7); ay3 += bfhi(u7);
        }
        for (; e < e1; ++e) {
            unsigned int u = h1h32[(size_t)srcs[e] * 64 + lane];
            ax0 += bflo(u); ay0 += bfhi(u);
        }
        float ax = (ax0 + ax1) + (ax2 + ax3);
        float ay = (ay0 + ay1) + (ay2 + ay3);
        int d = e1 - e0;
        float rd = (d > 0) ? (1.0f / (float)d) : 1.0f;
        unsigned int p = (unsigned int)f2bf(ax * rd) | ((unsigned int)f2bf(ay * rd) << 16);
        *reinterpret_cast<unsigned int*>(&A[nl][2 * lane]) = p;
    }
    __syncthreads();

    const int r15 = lane & 15, g4 = lane >> 4;
    const int n0 = wid * 32;
    f32x4 acc[2][2] = {};
    for (int kk = 0; kk < 8; ++kk) {
        short8 b0 = *reinterpret_cast<const short8*>(Bp2 + (((kk * 128 + n0 + r15) * 4 + g4) << 3));
        short8 b1 = *reinterpret_cast<const short8*>(Bp2 + (((kk * 128 + n0 + 16 + r15) * 4 + g4) << 3));
        #pragma unroll
        for (int mt = 0; mt < 2; ++mt) {
            short8 a = *reinterpret_cast<const short8*>(&A[mt * 16 + r15][kk * 32 + g4 * 8]);
            acc[mt][0] = __builtin_amdgcn_mfma_f32_16x16x32_bf16(a, b0, acc[mt][0], 0, 0, 0);
            acc[mt][1] = __builtin_amdgcn_mfma_f32_16x16x32_bf16(a, b1, acc[mt][1], 0, 0, 0);
        }
    }
    __syncthreads();
    float* h2L = reinterpret_cast<float*>(&A[0][0]);   // [32][132]
    #pragma unroll
    for (int mt = 0; mt < 2; ++mt)
        #pragma unroll
        for (int nt = 0; nt < 2; ++nt) {
            int col = n0 + nt * 16 + r15;
            float bb = b[col];
            #pragma unroll
            for (int reg = 0; reg < 4; ++reg) {
                int row = mt * 16 + g4 * 4 + reg;
                h2L[row * 132 + col] = fmaxf(acc[mt][nt][reg] + bb, 0.0f);
            }
        }
    __syncthreads();

    for (int t = tid; t < 352; t += 256) {       // heads
        int node = t / 11, o = t - node * 11;
        const float* h2 = &h2L[node * 132];
        if (o < 3) {
            float s = bh[o];
            for (int k = 0; k < 128; ++k) s += h2[k] * Wh[k * 3 + o];
            out1[(size_t)(tile + node) * 3 + o] = s;
        } else {
            int m = o - 3;
            float s = bm[m];
            for (int k = 0; k < 128; ++k) s += h2[k] * Wm[k * 8 + m];
            out2[(size_t)(tile + node) * 8 + m] = s;
        }
    }
}

extern "C" void kernel_launch(void* const* d_in, const int* in_sizes, int n_in,
                              void* d_out, int out_size, void* d_ws, size_t ws_size,
                              hipStream_t stream) {
    const float* x   = (const float*)d_in[0];
    const int*   ei  = (const int*)d_in[1];
    const int*   src = ei;
    const int*   dst = ei + N_EDGES;
    const float* Wl1 = (const float*)d_in[2];
    const float* Wr1 = (const float*)d_in[3];
    const float* b1  = (const float*)d_in[4];
    const float* Wl2 = (const float*)d_in[5];
    const float* Wr2 = (const float*)d_in[6];
    const float* b2  = (const float*)d_in[7];
    const float* Wh  = (const float*)d_in[8];
    const float* bh  = (const float*)d_in[9];
    const float* Wm  = (const float*)d_in[10];
    const float* bm  = (const float*)d_in[11];

    float* out1 = (float*)d_out;                   // [N,3]
    float* out2 = out1 + (size_t)N_NODES * 3;      // [N,8]

    char* ws = (char*)d_ws;
    int*   bcnt     = (int*)(ws);                           // 391 ints
    int*   bbase    = (int*)(ws + (64 << 10));              // 392 ints
    int*   ccur     = (int*)(ws + (128 << 10));             // 391 ints
    int*   rowstart = (int*)(ws + (512 << 10));             // 100001 ints
    unsigned int* pairs = (unsigned int*)(ws + (1536 << 10)); // 1.6M u32 (6.4MB)
    int*   srcs     = (int*)(ws + (8192 << 10));            // 1.6M ints (6.4MB)
    unsigned short* xh  = (unsigned short*)(ws + (15360 << 10)); // 6.4M bf16 (12.8MB)
    unsigned short* h1h = (unsigned short*)(ws + (28672 << 10)); // 12.8M bf16 (25.6MB)
    unsigned short* Bp1 = (unsigned short*)(ws + (54784 << 10)); // 16384 bf16 (32KB)
    unsigned short* Bp2 = (unsigned short*)(ws + (54848 << 10)); // 32768 bf16 (64KB)

    const int NBKT_BLKS = (N_EDGES + 256 * EPT - 1) / (256 * EPT);  // 98

    hipMemsetAsync(bcnt, 0, NBUCK * sizeof(int), stream);
    k_pre<<<6540, 256, 0, stream>>>(x, xh, dst, bcnt, Wl1, Wr1, Wl2, Wr2, Bp1, Bp2);
    k_scan391<<<1, 512, 0, stream>>>(bcnt, bbase, ccur);
    k_bucket<<<NBKT_BLKS, 256, 0, stream>>>(src, dst, ccur, pairs);
    k_csr<<<NBUCK, 256, 0, stream>>>(bbase, pairs, rowstart, srcs);

    k_layer1<<<3125, 256, 0, stream>>>(xh, rowstart, srcs, Bp1, b1, h1h);
    k_layer2<<<3125, 256, 0, stream>>>((const unsigned int*)h1h, rowstart, srcs,
                                       Bp2, b2, Wh, bh, Wm, bm, out1, out2);
}

// Round 12
// 280.305 us; speedup vs baseline: 1.1707x; 1.0759x over previous
//
#include <hip/hip_runtime.h>

#define N_NODES 100000
#define N_EDGES 1600000
#define NBUCK 391      // ceil(100000/256) coarse buckets
#define BSH 8          // 256 nodes per bucket
#define EPT 64         // edges per thread-slot in bucket phase (16384 edges/block, 98 blocks)
#define SLAB_SH 13     // 8192-edge slab per bucket (mean 4096, sigma ~64)

typedef __attribute__((ext_vector_type(8))) short short8;
typedef __attribute__((ext_vector_type(4))) float f32x4;

__device__ __forceinline__ float bflo(unsigned int u) { return __uint_as_float(u << 16); }
__device__ __forceinline__ float bfhi(unsigned int u) { return __uint_as_float(u & 0xffff0000u); }
__device__ __forceinline__ float bf2f(unsigned short u) { return __uint_as_float(((unsigned int)u) << 16); }
__device__ __forceinline__ unsigned short f2bf(float f) {
    unsigned int u = __float_as_uint(f);
    return (unsigned short)((u + 0x7fffu + ((u >> 16) & 1u)) >> 16);   // RNE
}

// ================= init slab cursors =================
__global__ __launch_bounds__(512) void k_init(int* __restrict__ ccur) {
    int t = threadIdx.x;
    if (t < NBUCK) ccur[t] = t << SLAB_SH;
}

// ================= mega-pre: cast x->bf16 | slab counting-sort | weight prepack =================
__global__ __launch_bounds__(256) void k_pre(
    const float* __restrict__ x, unsigned short* __restrict__ xh,
    const int* __restrict__ src, const int* __restrict__ dst,
    int* __restrict__ ccur, unsigned int* __restrict__ pairs,
    const float* __restrict__ Wl1, const float* __restrict__ Wr1,
    const float* __restrict__ Wl2, const float* __restrict__ Wr2,
    unsigned short* __restrict__ Bp1, unsigned short* __restrict__ Bp2)
{
    __shared__ int cnt[NBUCK];
    __shared__ int base[NBUCK];
    const int tid = threadIdx.x;
    if (blockIdx.x < 6250) {                        // ---- cast x (1.6M threads x 4 floats)
        int i = blockIdx.x * 256 + tid;
        float4 v = *reinterpret_cast<const float4*>(x + (size_t)i * 4);
        ushort4 o;
        o.x = f2bf(v.x); o.y = f2bf(v.y); o.z = f2bf(v.z); o.w = f2bf(v.w);
        *reinterpret_cast<ushort4*>(xh + (size_t)i * 4) = o;
    } else if (blockIdx.x < 6348) {                 // ---- slab bucket sort (98 blocks x 16384 edges)
        const int e_base = (blockIdx.x - 6250) * (256 * EPT);
        for (int i = tid; i < NBUCK; i += 256) cnt[i] = 0;
        __syncthreads();
        #pragma unroll
        for (int i = 0; i < EPT; ++i) {              // phase A: local histogram
            int e = e_base + i * 256 + tid;
            if (e < N_EDGES) atomicAdd(&cnt[dst[e] >> BSH], 1);
        }
        __syncthreads();
        for (int i = tid; i < NBUCK; i += 256) {     // phase B: reserve slab ranges
            int c = cnt[i];
            base[i] = (c > 0) ? atomicAdd(&ccur[i], c) : 0;
            cnt[i] = 0;
        }
        __syncthreads();
        #pragma unroll
        for (int i = 0; i < EPT; ++i) {              // phase C: grouped scatter
            int e = e_base + i * 256 + tid;
            if (e < N_EDGES) {
                int d = dst[e];
                int bkt = d >> BSH;
                int off = atomicAdd(&cnt[bkt], 1);
                pairs[base[bkt] + off] = ((unsigned int)(d & 255) << 17) | (unsigned int)src[e];
            }
        }
    } else {                                        // ---- weight prepack (192 blocks)
        int idx = (blockIdx.x - 6348) * 256 + tid;
        if (idx < 16384) {                          // layer1: K=128
            int j = idx & 7, g = (idx >> 3) & 3, col = (idx >> 5) & 127, kk = idx >> 12;
            int r = kk * 32 + g * 8 + j;
            float w = (r < 64) ? Wl1[r * 128 + col] : Wr1[(r - 64) * 128 + col];
            Bp1[idx] = f2bf(w);
        } else {                                    // layer2: K=256
            int q = idx - 16384;
            int j = q & 7, g = (q >> 3) & 3, col = (q >> 5) & 127, kk = q >> 12;
            int r = kk * 32 + g * 8 + j;
            float w = (r < 128) ? Wl2[r * 128 + col] : Wr2[(r - 128) * 128 + col];
            Bp2[q] = f2bf(w);
        }
    }
}

// ================= CSR: per-bucket hist + scan -> rowpad[391*257]; exact scatter to srcs slab =================
__global__ __launch_bounds__(256) void k_csr(const int* __restrict__ ccur,
                                             const unsigned int* __restrict__ pairs,
                                             int* __restrict__ rowpad, int* __restrict__ srcs) {
    __shared__ int nh[256];       // per-node counts -> cursors
    __shared__ int wsum[4];
    const int c = blockIdx.x, tid = threadIdx.x, lane = tid & 63, wid = tid >> 6;
    const int e0 = c << SLAB_SH, e1 = ccur[c];

    nh[tid] = 0;
    __syncthreads();
    for (int e = e0 + tid; e < e1; e += 256)     // phase A: node histogram from pairs (L2-hot re-read later)
        atomicAdd(&nh[pairs[e] >> 17], 1);
    __syncthreads();
    int v = nh[tid];                              // phase B: scan 256 counts
    int s = v;
    #pragma unroll
    for (int off = 1; off < 64; off <<= 1) {
        int t = __shfl_up(s, off);
        if (lane >= off) s += t;
    }
    if (lane == 63) wsum[wid] = s;
    __syncthreads();
    if (tid < 4) {
        int w = wsum[tid];
        #pragma unroll
        for (int off = 1; off < 4; off <<= 1) {
            int t = __shfl_up(w, off);
            if (tid >= off) w += t;
        }
        wsum[tid] = w;
    }
    __syncthreads();
    int excl = e0 + ((wid == 0) ? 0 : wsum[wid - 1]) + s - v;
    rowpad[c * 257 + tid] = excl;                 // coalesced rowstart write (bucket-local CSR)
    if (tid == 0) rowpad[c * 257 + 256] = e1;     // bucket end sentinel
    __syncthreads();
    nh[tid] = excl;                               // reuse as cursors
    __syncthreads();
    for (int e = e0 + tid; e < e1; e += 256) {    // phase C: exact scatter (LDS cursors, L2-hot)
        unsigned int u = pairs[e];
        int p = atomicAdd(&nh[u >> 17], 1);
        srcs[p] = (int)(u & 0x1FFFFu);
    }
}

// ================= layer 1: gather(bf16, unroll-8) + MFMA dense + relu -> bf16 h1h =================
__global__ __launch_bounds__(256, 8) void k_layer1(
    const unsigned short* __restrict__ xh,
    const int* __restrict__ rowpad, const int* __restrict__ srcs,
    const unsigned short* __restrict__ Bp1, const float* __restrict__ b,
    unsigned short* __restrict__ h1h)
{
    __shared__ unsigned short A[32][136];
    __shared__ int rs[33];
    const int tile = blockIdx.x * 32;           // 100000 = 3125*32
    const int tid = threadIdx.x, lane = tid & 63, wid = tid >> 6;

    if (tid < 33) rs[tid] = rowpad[(tile >> 8) * 257 + (tile & 255) + tid];
    {   // root rows -> cols 64..127
        int node = tid >> 3, part = tid & 7;
        uint4 v = *reinterpret_cast<const uint4*>(xh + (size_t)(tile + node) * 64 + part * 8);
        *reinterpret_cast<uint4*>(&A[node][64 + part * 8]) = v;
    }
    __syncthreads();

    for (int it = 0; it < 8; ++it) {            // wave-per-node gather, unroll-8
        int nl = wid * 8 + it;
        int e0 = rs[nl], e1 = rs[nl + 1];
        float a0 = 0.f, a1 = 0.f, a2 = 0.f, a3 = 0.f;
        int e = e0;
        for (; e + 8 <= e1; e += 8) {
            int s0 = srcs[e],     s1 = srcs[e + 1], s2 = srcs[e + 2], s3 = srcs[e + 3];
            int s4 = srcs[e + 4], s5 = srcs[e + 5], s6 = srcs[e + 6], s7 = srcs[e + 7];
            float v0 = bf2f(xh[(size_t)s0 * 64 + lane]);
            float v1 = bf2f(xh[(size_t)s1 * 64 + lane]);
            float v2 = bf2f(xh[(size_t)s2 * 64 + lane]);
            float v3 = bf2f(xh[(size_t)s3 * 64 + lane]);
            float v4 = bf2f(xh[(size_t)s4 * 64 + lane]);
            float v5 = bf2f(xh[(size_t)s5 * 64 + lane]);
            float v6 = bf2f(xh[(size_t)s6 * 64 + lane]);
            float v7 = bf2f(xh[(size_t)s7 * 64 + lane]);
            a0 += v0; a1 += v1; a2 += v2; a3 += v3;
            a0 += v4; a1 += v5; a2 += v6; a3 += v7;
        }
        for (; e < e1; ++e)
            a0 += bf2f(xh[(size_t)srcs[e] * 64 + lane]);
        float acc = (a0 + a1) + (a2 + a3);
        int d = e1 - e0;
        A[nl][lane] = f2bf(acc * ((d > 0) ? (1.0f / (float)d) : 1.0f));
    }
    __syncthreads();

    const int r15 = lane & 15, g4 = lane >> 4;
    const int n0 = wid * 32;
    f32x4 acc[2][2] = {};
    for (int kk = 0; kk < 4; ++kk) {
        short8 b0 = *reinterpret_cast<const short8*>(Bp1 + (((kk * 128 + n0 + r15) * 4 + g4) << 3));
        short8 b1 = *reinterpret_cast<const short8*>(Bp1 + (((kk * 128 + n0 + 16 + r15) * 4 + g4) << 3));
        #pragma unroll
        for (int mt = 0; mt < 2; ++mt) {
            short8 a = *reinterpret_cast<const short8*>(&A[mt * 16 + r15][kk * 32 + g4 * 8]);
            acc[mt][0] = __builtin_amdgcn_mfma_f32_16x16x32_bf16(a, b0, acc[mt][0], 0, 0, 0);
            acc[mt][1] = __builtin_amdgcn_mfma_f32_16x16x32_bf16(a, b1, acc[mt][1], 0, 0, 0);
        }
    }
    #pragma unroll
    for (int mt = 0; mt < 2; ++mt)
        #pragma unroll
        for (int nt = 0; nt < 2; ++nt) {
            int col = n0 + nt * 16 + r15;
            float bb = b[col];
            #pragma unroll
            for (int reg = 0; reg < 4; ++reg) {
                int row = tile + mt * 16 + g4 * 4 + reg;
                h1h[(size_t)row * 128 + col] = f2bf(fmaxf(acc[mt][nt][reg] + bb, 0.0f));
            }
        }
}

// ================= layer 2 + heads: gather(bf16x2, unroll-8) + MFMA dense + relu + heads =================
__global__ __launch_bounds__(256, 8) void k_layer2(
    const unsigned int* __restrict__ h1h32,
    const int* __restrict__ rowpad, const int* __restrict__ srcs,
    const unsigned short* __restrict__ Bp2, const float* __restrict__ b,
    const float* __restrict__ Wh, const float* __restrict__ bh,
    const float* __restrict__ Wm, const float* __restrict__ bm,
    float* __restrict__ out1, float* __restrict__ out2)
{
    __shared__ unsigned short A[32][264];
    __shared__ int rs[33];
    const int tile = blockIdx.x * 32;
    const int tid = threadIdx.x, lane = tid & 63, wid = tid >> 6;

    if (tid < 33) rs[tid] = rowpad[(tile >> 8) * 257 + (tile & 255) + tid];
    {   // root rows -> cols 128..255
        int node = tid >> 3, part = tid & 7;
        const unsigned int* p = h1h32 + (size_t)(tile + node) * 64 + part * 8;
        uint4 v0 = *reinterpret_cast<const uint4*>(p);
        uint4 v1 = *reinterpret_cast<const uint4*>(p + 4);
        *reinterpret_cast<uint4*>(&A[node][128 + part * 16]) = v0;
        *reinterpret_cast<uint4*>(&A[node][128 + part * 16 + 8]) = v1;
    }
    __syncthreads();

    for (int it = 0; it < 8; ++it) {            // wave-per-node gather, unroll-8
        int nl = wid * 8 + it;
        int e0 = rs[nl], e1 = rs[nl + 1];
        float ax0 = 0.f, ax1 = 0.f, ax2 = 0.f, ax3 = 0.f;
        float ay0 = 0.f, ay1 = 0.f, ay2 = 0.f, ay3 = 0.f;
        int e = e0;
        for (; e + 8 <= e1; e += 8) {
            int s0 = srcs[e],     s1 = srcs[e + 1], s2 = srcs[e + 2], s3 = srcs[e + 3];
            int s4 = srcs[e + 4], s5 = srcs[e + 5], s6 = srcs[e + 6], s7 = srcs[e + 7];
            unsigned int u0 = h1h32[(size_t)s0 * 64 + lane];
            unsigned int u1 = h1h32[(size_t)s1 * 64 + lane];
            unsigned int u2 = h1h32[(size_t)s2 * 64 + lane];
            unsigned int u3 = h1h32[(size_t)s3 * 64 + lane];
            unsigned int u4 = h1h32[(size_t)s4 * 64 + lane];
            unsigned int u5 = h1h32[(size_t)s5 * 64 + lane];
            unsigned int u6 = h1h32[(size_t)s6 * 64 + lane];
            unsigned int u7 = h1h32[(size_t)s7 * 64 + lane];
            ax0 += bflo(u0); ay0 += bfhi(u0);
            ax1 += bflo(u1); ay1 += bfhi(u1);
            ax2 += bflo(u2); ay2 += bfhi(u2);
            ax3 += bflo(u3); ay3 += bfhi(u3);
            ax0 += bflo(u4); ay0 += bfhi(u4);
            ax1 += bflo(u5); ay1 += bfhi(u5);
            ax2 += bflo(u6); ay2 += bfhi(u6);
            ax3 += bflo(u7); ay3 += bfhi(u7);
        }
        for (; e < e1; ++e) {
            unsigned int u = h1h32[(size_t)srcs[e] * 64 + lane];
            ax0 += bflo(u); ay0 += bfhi(u);
        }
        float ax = (ax0 + ax1) + (ax2 + ax3);
        float ay = (ay0 + ay1) + (ay2 + ay3);
        int d = e1 - e0;
        float rd = (d > 0) ? (1.0f / (float)d) : 1.0f;
        unsigned int p = (unsigned int)f2bf(ax * rd) | ((unsigned int)f2bf(ay * rd) << 16);
        *reinterpret_cast<unsigned int*>(&A[nl][2 * lane]) = p;
    }
    __syncthreads();

    const int r15 = lane & 15, g4 = lane >> 4;
    const int n0 = wid * 32;
    f32x4 acc[2][2] = {};
    for (int kk = 0; kk < 8; ++kk) {
        short8 b0 = *reinterpret_cast<const short8*>(Bp2 + (((kk * 128 + n0 + r15) * 4 + g4) << 3));
        short8 b1 = *reinterpret_cast<const short8*>(Bp2 + (((kk * 128 + n0 + 16 + r15) * 4 + g4) << 3));
        #pragma unroll
        for (int mt = 0; mt < 2; ++mt) {
            short8 a = *reinterpret_cast<const short8*>(&A[mt * 16 + r15][kk * 32 + g4 * 8]);
            acc[mt][0] = __builtin_amdgcn_mfma_f32_16x16x32_bf16(a, b0, acc[mt][0], 0, 0, 0);
            acc[mt][1] = __builtin_amdgcn_mfma_f32_16x16x32_bf16(a, b1, acc[mt][1], 0, 0, 0);
        }
    }
    __syncthreads();
    float* h2L = reinterpret_cast<float*>(&A[0][0]);   // [32][132]
    #pragma unroll
    for (int mt = 0; mt < 2; ++mt)
        #pragma unroll
        for (int nt = 0; nt < 2; ++nt) {
            int col = n0 + nt * 16 + r15;
            float bb = b[col];
            #pragma unroll
            for (int reg = 0; reg < 4; ++reg) {
                int row = mt * 16 + g4 * 4 + reg;
                h2L[row * 132 + col] = fmaxf(acc[mt][nt][reg] + bb, 0.0f);
            }
        }
    __syncthreads();

    for (int t = tid; t < 352; t += 256) {       // heads
        int node = t / 11, o = t - node * 11;
        const float* h2 = &h2L[node * 132];
        if (o < 3) {
            float s = bh[o];
            for (int k = 0; k < 128; ++k) s += h2[k] * Wh[k * 3 + o];
            out1[(size_t)(tile + node) * 3 + o] = s;
        } else {
            int m = o - 3;
            float s = bm[m];
            for (int k = 0; k < 128; ++k) s += h2[k] * Wm[k * 8 + m];
            out2[(size_t)(tile + node) * 8 + m] = s;
        }
    }
}

extern "C" void kernel_launch(void* const* d_in, const int* in_sizes, int n_in,
                              void* d_out, int out_size, void* d_ws, size_t ws_size,
                              hipStream_t stream) {
    const float* x   = (const float*)d_in[0];
    const int*   ei  = (const int*)d_in[1];
    const int*   src = ei;
    const int*   dst = ei + N_EDGES;
    const float* Wl1 = (const float*)d_in[2];
    const float* Wr1 = (const float*)d_in[3];
    const float* b1  = (const float*)d_in[4];
    const float* Wl2 = (const float*)d_in[5];
    const float* Wr2 = (const float*)d_in[6];
    const float* b2  = (const float*)d_in[7];
    const float* Wh  = (const float*)d_in[8];
    const float* bh  = (const float*)d_in[9];
    const float* Wm  = (const float*)d_in[10];
    const float* bm  = (const float*)d_in[11];

    float* out1 = (float*)d_out;                   // [N,3]
    float* out2 = out1 + (size_t)N_NODES * 3;      // [N,8]

    char* ws = (char*)d_ws;
    int*   ccur     = (int*)(ws);                            // 391 ints
    int*   rowpad   = (int*)(ws + (64 << 10));               // 391*257 ints (402KB)
    unsigned int* pairs = (unsigned int*)(ws + (1024 << 10)); // 391*8192 u32 (12.5MB)
    int*   srcs     = (int*)(ws + (14336 << 10));            // 391*8192 ints (12.5MB)
    unsigned short* xh  = (unsigned short*)(ws + (27648 << 10)); // 6.4M bf16 (12.8MB)
    unsigned short* h1h = (unsigned short*)(ws + (40960 << 10)); // 12.8M bf16 (25.6MB)
    unsigned short* Bp1 = (unsigned short*)(ws + (66560 << 10)); // 16384 bf16 (32KB)
    unsigned short* Bp2 = (unsigned short*)(ws + (66592 << 10)); // 32768 bf16 (64KB)

    k_init<<<1, 512, 0, stream>>>(ccur);
    k_pre<<<6540, 256, 0, stream>>>(x, xh, src, dst, ccur, pairs, Wl1, Wr1, Wl2, Wr2, Bp1, Bp2);
    k_csr<<<NBUCK, 256, 0, stream>>>(ccur, pairs, rowpad, srcs);

    k_layer1<<<3125, 256, 0, stream>>>(xh, rowpad, srcs, Bp1, b1, h1h);
    k_layer2<<<3125, 256, 0, stream>>>((const unsigned int*)h1h, rowpad, srcs,
                                       Bp2, b2, Wh, bh, Wm, bm, out1, out2);
}